// Round 3
// baseline (1851.167 us; speedup 1.0000x reference)
//
#include <hip/hip_runtime.h>
#include <hip/hip_bf16.h>

#define D_IN 384
#define D_H  64
#define BSH  7          // bucket shift: 128 nodes per bucket
#define BN   128        // nodes per bucket
#define PAD  16         // counter padding (ints) -> one 64B line per counter
#define EBUF 4608       // staged edges per bucket (mean 4092, +8 sigma margin)

typedef __attribute__((ext_vector_type(8))) short short8;
typedef __attribute__((ext_vector_type(4))) float f32x4;

__device__ __forceinline__ unsigned short f2bf(float f){
  unsigned u = __float_as_uint(f);
  u += 0x7fffu + ((u >> 16) & 1u);   // round-to-nearest-even
  return (unsigned short)(u >> 16);
}
__device__ __forceinline__ float bf2f(unsigned short u){
  return __uint_as_float((unsigned)u << 16);
}

// ---- K0: zero padded bucket counters ----
__global__ void k_binit(int* bcnt, int n){
  int i = blockIdx.x * blockDim.x + threadIdx.x;
  if (i < n) bcnt[i] = 0;
}

// ---- K1: per-block LDS histogram of dst buckets, merge to padded globals ----
__global__ __launch_bounds__(256) void k_bcount(const int* __restrict__ ei,
                                                int* bcnt, int E, int NB){
  __shared__ int hist[1024];
  int t = threadIdx.x;
  for (int i = t; i < NB; i += 256) hist[i] = 0;
  __syncthreads();
  for (int e = blockIdx.x * 256 + t; e < E; e += gridDim.x * 256)
    atomicAdd(&hist[ei[E + e] >> BSH], 1);
  __syncthreads();
  for (int i = t; i < NB; i += 256){
    int v = hist[i];
    if (v) atomicAdd(&bcnt[i * PAD], v);
  }
}

// ---- K2: single-block scan over bucket counts -> bstart, init cursors ----
__global__ __launch_bounds__(1024) void k_bscan(const int* __restrict__ bcnt,
                                                int* bstart, int* bcur, int NB, int E){
  __shared__ int sd[1024];
  int t = threadIdx.x;
  int c = (t < NB) ? bcnt[t * PAD] : 0;
  sd[t] = c;
  __syncthreads();
  for (int off = 1; off < 1024; off <<= 1){
    int v = (t >= off) ? sd[t - off] : 0;
    __syncthreads();
    sd[t] += v;
    __syncthreads();
  }
  if (t < NB){
    int excl = sd[t] - c;
    bstart[t] = excl;
    bcur[t * PAD] = excl;
  }
  if (t == 0) bstart[NB] = E;
}

// ---- K3: scatter packed (dlocal,src) into bucket-major order ----
// writes concentrate in each bucket's active window -> full-line writebacks
__global__ void k_bscatter(const int* __restrict__ ei, int* bcur,
                           unsigned* __restrict__ bscat, int E){
  int e = blockIdx.x * blockDim.x + threadIdx.x;
  if (e >= E) return;
  int s = ei[e];
  int d = ei[E + e];
  int b = d >> BSH;
  int pos = atomicAdd(&bcur[b * PAD], 1);
  bscat[pos] = ((unsigned)(d & (BN - 1)) << 17) | (unsigned)s;
}

// ---- K4: per-bucket degree count (LDS) -> dis = rsqrt(deg+1) ----
__global__ __launch_bounds__(256) void k_deg(const unsigned* __restrict__ bscat,
                                             const int* __restrict__ bstart,
                                             float* __restrict__ dis, int N){
  __shared__ int cnt[BN];
  int b = blockIdx.x;
  int t = threadIdx.x;
  if (t < BN) cnt[t] = 0;
  __syncthreads();
  int es = bstart[b], ee = bstart[b + 1];
  for (int e = es + t; e < ee; e += 256)
    atomicAdd(&cnt[bscat[e] >> 17], 1);
  __syncthreads();
  if (t < BN){
    int node = b * BN + t;
    if (node < N) dis[node] = rsqrtf((float)(cnt[t] + 1));
  }
}

// ---- K5: hb = bf16( (x @ W_gcn) * dis[row] )  -- pre-scaled by dis[src] ----
__global__ __launch_bounds__(256) void k_gemm(const float* __restrict__ x,
                                              const float* __restrict__ W,
                                              const float* __restrict__ dis,
                                              unsigned short* __restrict__ hb, int N){
  __shared__ __align__(16) short a_sw[4 * 4 * 64 * 8];  // 16 KiB
  __shared__ __align__(16) short b_sw[4 * 4 * 64 * 8];  // 16 KiB
  const int t = threadIdx.x;
  const int node0 = blockIdx.x * 64;
  const int w = t >> 6;
  const int l = t & 63;

  f32x4 acc[4];
  #pragma unroll
  for (int nt = 0; nt < 4; nt++) acc[nt] = (f32x4){0.f, 0.f, 0.f, 0.f};

  for (int c = 0; c < 3; c++){
    const int kbase = c * 128;
    #pragma unroll
    for (int r = 0; r < 4; r++){
      int id  = t + 256 * r;
      int cl  = id & 63;
      int s   = (id >> 6) & 3;
      int tl  = id >> 8;
      int k   = kbase + s * 32 + ((cl >> 4) << 3);
      {
        int node = node0 + tl * 16 + (cl & 15);
        uint4 pv;
        if (node < N){
          const float* xp = &x[(size_t)node * D_IN + k];
          float4 u0 = *(const float4*)xp;
          float4 u1 = *(const float4*)(xp + 4);
          pv.x = (unsigned)f2bf(u0.x) | ((unsigned)f2bf(u0.y) << 16);
          pv.y = (unsigned)f2bf(u0.z) | ((unsigned)f2bf(u0.w) << 16);
          pv.z = (unsigned)f2bf(u1.x) | ((unsigned)f2bf(u1.y) << 16);
          pv.w = (unsigned)f2bf(u1.z) | ((unsigned)f2bf(u1.w) << 16);
        } else {
          pv.x = pv.y = pv.z = pv.w = 0u;
        }
        *reinterpret_cast<uint4*>(&a_sw[id * 8]) = pv;
      }
      {
        int n = tl * 16 + (cl & 15);
        const float* wp = &W[(size_t)k * D_H + n];
        uint4 qv;
        qv.x = (unsigned)f2bf(wp[0])   | ((unsigned)f2bf(wp[64])  << 16);
        qv.y = (unsigned)f2bf(wp[128]) | ((unsigned)f2bf(wp[192]) << 16);
        qv.z = (unsigned)f2bf(wp[256]) | ((unsigned)f2bf(wp[320]) << 16);
        qv.w = (unsigned)f2bf(wp[384]) | ((unsigned)f2bf(wp[448]) << 16);
        *reinterpret_cast<uint4*>(&b_sw[id * 8]) = qv;
      }
    }
    __syncthreads();
    #pragma unroll
    for (int s = 0; s < 4; s++){
      short8 a = *reinterpret_cast<const short8*>(&a_sw[((w * 4 + s) * 64 + l) * 8]);
      #pragma unroll
      for (int nt = 0; nt < 4; nt++){
        short8 b = *reinterpret_cast<const short8*>(&b_sw[((nt * 4 + s) * 64 + l) * 8]);
        acc[nt] = __builtin_amdgcn_mfma_f32_16x16x32_bf16(a, b, acc[nt], 0, 0, 0);
      }
    }
    __syncthreads();
  }
  const int qd = l >> 4;
  const int col0 = l & 15;
  #pragma unroll
  for (int r = 0; r < 4; r++){
    int node = node0 + w * 16 + qd * 4 + r;
    if (node < N){
      float scale = dis[node];
      #pragma unroll
      for (int nt = 0; nt < 4; nt++)
        hb[(size_t)node * D_H + nt * 16 + col0] = f2bf(acc[nt][r] * scale);
    }
  }
}

// ---- K6: fused per-bucket aggregation into LDS accumulators ----
// wg per bucket: hacc[128][64] fp32 in LDS; edges staged in LDS; each wave
// processes 8 edges/iter: coalesced 128B hb row gather + ds_add_f32.
__global__ __launch_bounds__(512) void k_agg(const unsigned short* __restrict__ hb,
                                             const unsigned* __restrict__ bscat,
                                             const int* __restrict__ bstart,
                                             const float* __restrict__ dis,
                                             const float* __restrict__ bg,
                                             float* __restrict__ hout, int N){
  __shared__ float hacc[BN * D_H];       // 32 KiB
  __shared__ unsigned ebuf[EBUF];        // 18 KiB
  const int b = blockIdx.x;
  const int t = threadIdx.x;
  const int nb0 = b * BN;
  const int es = bstart[b], ee = bstart[b + 1];
  const int cnt = ee - es;
  const int stage = cnt < EBUF ? cnt : EBUF;

  // init accumulators with the self-loop term hb[i] (= h[i]*dis[i])
  for (int idx = t; idx < BN * D_H; idx += 512){
    int node = nb0 + (idx >> 6);
    hacc[idx] = (node < N) ? bf2f(hb[(size_t)nb0 * D_H + idx]) : 0.f;
  }
  // stage packed edges
  for (int i = t; i < stage; i += 512) ebuf[i] = bscat[es + i];
  __syncthreads();

  const int w = t >> 6;     // wave 0..7
  const int f = t & 63;
  for (int base = w * 8; base < cnt; base += 64){
    #pragma unroll
    for (int j = 0; j < 8; j++){
      int i = base + j;
      if (i < cnt){
        unsigned p = (i < stage) ? ebuf[i] : bscat[es + i];
        float v = bf2f(hb[(size_t)(p & 0x1FFFFu) * D_H + f]);
        atomicAdd(&hacc[(p >> 17) * D_H + f], v);
      }
    }
  }
  __syncthreads();

  // epilogue: *dis[dst] + bias, relu
  for (int idx = t; idx < BN * D_H; idx += 512){
    int node = nb0 + (idx >> 6);
    if (node < N){
      float v = hacc[idx] * dis[node] + bg[idx & 63];
      hout[(size_t)nb0 * D_H + idx] = v > 0.f ? v : 0.f;
    }
  }
}

// ---- K7: pool (sorted batch -> binary search range) + classifier ----
__global__ void k_pool(const float* __restrict__ hout, const int* __restrict__ batch,
                       const float* __restrict__ wc, const float* __restrict__ bc,
                       float* __restrict__ out, int N, int G){
  int g = blockIdx.x;
  int t = threadIdx.x;
  int lo = 0, hi = N;
  while (lo < hi){ int m = (lo + hi) >> 1; if (batch[m] < g) lo = m + 1; else hi = m; }
  int start = lo;
  lo = start; hi = N;
  while (lo < hi){ int m = (lo + hi) >> 1; if (batch[m] < g + 1) lo = m + 1; else hi = m; }
  int end = lo;

  int f = t & 63;
  int r = t >> 6;
  float sum = 0.f;
  for (int i = start + r; i < end; i += 4) sum += hout[(size_t)i * D_H + f];
  __shared__ float red[256];
  red[t] = sum;
  __syncthreads();
  if (t < 64){
    float z = red[t] + red[t + 64] + red[t + 128] + red[t + 192];
    float p = z * wc[t];
    #pragma unroll
    for (int off = 32; off > 0; off >>= 1) p += __shfl_down(p, off);
    if (t == 0) out[g] = p + bc[0];
  }
}

extern "C" void kernel_launch(void* const* d_in, const int* in_sizes, int n_in,
                              void* d_out, int out_size, void* d_ws, size_t ws_size,
                              hipStream_t stream){
  const float* x     = (const float*)d_in[0];
  const int*   ei    = (const int*)d_in[1];    // [2,E] flat: [0..E)=src, [E..2E)=dst
  const int*   batch = (const int*)d_in[2];
  const float* Wg    = (const float*)d_in[3];
  const float* bg    = (const float*)d_in[4];
  const float* wc    = (const float*)d_in[5];
  const float* bc    = (const float*)d_in[6];
  float* out = (float*)d_out;

  const int N = in_sizes[2];
  const int E = in_sizes[1] / 2;
  const int G = out_size;
  const int NB = (N + BN - 1) / BN;   // 782 for N=100000 (<=1024 assumed)

  char* ws = (char*)d_ws;
  size_t off = 0;
  auto alloc = [&](size_t bytes) -> void* {
    void* p = ws + off;
    off += (bytes + 255) & ~(size_t)255;
    return p;
  };
  int*            bcnt   = (int*)           alloc((size_t)NB * PAD * 4);
  int*            bcur   = (int*)           alloc((size_t)NB * PAD * 4);
  int*            bstart = (int*)           alloc((size_t)(NB + 1) * 4);
  unsigned*       bscat  = (unsigned*)      alloc((size_t)E * 4);
  float*          dis    = (float*)         alloc((size_t)N * 4);
  unsigned short* hb     = (unsigned short*)alloc((size_t)N * D_H * 2);
  float*          hout   = (float*)         alloc((size_t)N * D_H * 4);

  k_binit   <<<(NB * PAD + 255) / 256, 256, 0, stream>>>(bcnt, NB * PAD);
  k_bcount  <<<512, 256, 0, stream>>>(ei, bcnt, E, NB);
  k_bscan   <<<1, 1024, 0, stream>>>(bcnt, bstart, bcur, NB, E);
  k_bscatter<<<(E + 255) / 256, 256, 0, stream>>>(ei, bcur, bscat, E);
  k_deg     <<<NB, 256, 0, stream>>>(bscat, bstart, dis, N);
  k_gemm    <<<(N + 63) / 64, 256, 0, stream>>>(x, Wg, dis, hb, N);
  k_agg     <<<NB, 512, 0, stream>>>(hb, bscat, bstart, dis, bg, hout, N);
  k_pool    <<<G, 256, 0, stream>>>(hout, batch, wc, bc, out, N, G);
}

// Round 4
// 609.845 us; speedup vs baseline: 3.0355x; 3.0355x over previous
//
#include <hip/hip_runtime.h>
#include <hip/hip_bf16.h>

#define D_IN 384
#define D_H  64
#define BSH  7          // bucket shift: 128 nodes per bucket
#define BN   128        // nodes per bucket
#define PAD  16         // counter padding (ints) -> one 64B line per counter
#define EBUF 4608       // staged edges per bucket (mean 4092, +8 sigma margin)

typedef __attribute__((ext_vector_type(8))) short short8;
typedef __attribute__((ext_vector_type(4))) float f32x4;

__device__ __forceinline__ unsigned short f2bf(float f){
  unsigned u = __float_as_uint(f);
  u += 0x7fffu + ((u >> 16) & 1u);   // round-to-nearest-even
  return (unsigned short)(u >> 16);
}
__device__ __forceinline__ float bf2f(unsigned short u){
  return __uint_as_float((unsigned)u << 16);
}

// ---- K0: zero padded bucket counters ----
__global__ void k_binit(int* bcnt, int n){
  int i = blockIdx.x * blockDim.x + threadIdx.x;
  if (i < n) bcnt[i] = 0;
}

// ---- K1: per-block LDS histogram of dst buckets, merge to padded globals ----
__global__ __launch_bounds__(256) void k_bcount(const int* __restrict__ ei,
                                                int* bcnt, int E, int NB){
  __shared__ int hist[1024];
  int t = threadIdx.x;
  for (int i = t; i < NB; i += 256) hist[i] = 0;
  __syncthreads();
  for (int e = blockIdx.x * 256 + t; e < E; e += gridDim.x * 256)
    atomicAdd(&hist[ei[E + e] >> BSH], 1);
  __syncthreads();
  for (int i = t; i < NB; i += 256){
    int v = hist[i];
    if (v) atomicAdd(&bcnt[i * PAD], v);
  }
}

// ---- K2: single-block scan over bucket counts -> bstart, init cursors ----
__global__ __launch_bounds__(1024) void k_bscan(const int* __restrict__ bcnt,
                                                int* bstart, int* bcur, int NB, int E){
  __shared__ int sd[1024];
  int t = threadIdx.x;
  int c = (t < NB) ? bcnt[t * PAD] : 0;
  sd[t] = c;
  __syncthreads();
  for (int off = 1; off < 1024; off <<= 1){
    int v = (t >= off) ? sd[t - off] : 0;
    __syncthreads();
    sd[t] += v;
    __syncthreads();
  }
  if (t < NB){
    int excl = sd[t] - c;
    bstart[t] = excl;
    bcur[t * PAD] = excl;
  }
  if (t == 0) bstart[NB] = E;
}

// ---- K3: scatter packed (dlocal,src) into bucket-major order ----
// writes concentrate in each bucket's rolling 16KB window -> full-line writebacks
__global__ void k_bscatter(const int* __restrict__ ei, int* bcur,
                           unsigned* __restrict__ bscat, int E){
  int e = blockIdx.x * blockDim.x + threadIdx.x;
  if (e >= E) return;
  int s = ei[e];
  int d = ei[E + e];
  int b = d >> BSH;
  int pos = atomicAdd(&bcur[b * PAD], 1);
  bscat[pos] = ((unsigned)(d & (BN - 1)) << 17) | (unsigned)s;
}

// ---- K4: per-bucket counting sort -> node-major csr, rowstart, dis ----
// int LDS atomics only (native ds_add). All csr writes land in the bucket's
// 16KB window.
__global__ __launch_bounds__(256) void k_nodecsr(const unsigned* __restrict__ bscat,
                                                 const int* __restrict__ bstart,
                                                 int* __restrict__ csr,
                                                 int* __restrict__ rowstart,
                                                 float* __restrict__ dis,
                                                 int N, int NB, int E){
  __shared__ int lcnt[BN];
  __shared__ int sc[BN];
  __shared__ int lcur[BN];
  __shared__ unsigned ebuf[EBUF];
  const int b = blockIdx.x;
  const int t = threadIdx.x;
  const int es = bstart[b], ee = bstart[b + 1];
  const int cnt = ee - es;

  if (t < BN) lcnt[t] = 0;
  __syncthreads();
  for (int i = t; i < cnt; i += 256){
    unsigned p = bscat[es + i];
    if (i < EBUF) ebuf[i] = p;
    atomicAdd(&lcnt[p >> 17], 1);
  }
  __syncthreads();
  // exclusive scan over 128 counts (Hillis-Steele, barriers hit by all threads)
  if (t < BN) sc[t] = lcnt[t];
  __syncthreads();
  for (int off = 1; off < BN; off <<= 1){
    int v = (t < BN && t >= off) ? sc[t - off] : 0;
    __syncthreads();
    if (t < BN) sc[t] += v;
    __syncthreads();
  }
  if (t < BN){
    int excl = sc[t] - lcnt[t];
    lcur[t] = excl;
    int node = b * BN + t;
    if (node < N){
      rowstart[node] = es + excl;
      dis[node] = rsqrtf((float)(lcnt[t] + 1));
    }
  }
  if (b == NB - 1 && t == 0) rowstart[N] = E;
  __syncthreads();
  // re-scatter into node-major order within the bucket window
  for (int i = t; i < cnt; i += 256){
    unsigned p = (i < EBUF) ? ebuf[i] : bscat[es + i];
    int pos = atomicAdd(&lcur[p >> 17], 1);
    csr[es + pos] = (int)(p & 0x1FFFFu);
  }
}

// ---- K5: hb = bf16( (x @ W_gcn) * dis[row] )  -- pre-scaled by dis[src] ----
__global__ __launch_bounds__(256) void k_gemm(const float* __restrict__ x,
                                              const float* __restrict__ W,
                                              const float* __restrict__ dis,
                                              unsigned short* __restrict__ hb, int N){
  __shared__ __align__(16) short a_sw[4 * 4 * 64 * 8];  // 16 KiB
  __shared__ __align__(16) short b_sw[4 * 4 * 64 * 8];  // 16 KiB
  const int t = threadIdx.x;
  const int node0 = blockIdx.x * 64;
  const int w = t >> 6;
  const int l = t & 63;

  f32x4 acc[4];
  #pragma unroll
  for (int nt = 0; nt < 4; nt++) acc[nt] = (f32x4){0.f, 0.f, 0.f, 0.f};

  for (int c = 0; c < 3; c++){
    const int kbase = c * 128;
    #pragma unroll
    for (int r = 0; r < 4; r++){
      int id  = t + 256 * r;
      int cl  = id & 63;
      int s   = (id >> 6) & 3;
      int tl  = id >> 8;
      int k   = kbase + s * 32 + ((cl >> 4) << 3);
      {
        int node = node0 + tl * 16 + (cl & 15);
        uint4 pv;
        if (node < N){
          const float* xp = &x[(size_t)node * D_IN + k];
          float4 u0 = *(const float4*)xp;
          float4 u1 = *(const float4*)(xp + 4);
          pv.x = (unsigned)f2bf(u0.x) | ((unsigned)f2bf(u0.y) << 16);
          pv.y = (unsigned)f2bf(u0.z) | ((unsigned)f2bf(u0.w) << 16);
          pv.z = (unsigned)f2bf(u1.x) | ((unsigned)f2bf(u1.y) << 16);
          pv.w = (unsigned)f2bf(u1.z) | ((unsigned)f2bf(u1.w) << 16);
        } else {
          pv.x = pv.y = pv.z = pv.w = 0u;
        }
        *reinterpret_cast<uint4*>(&a_sw[id * 8]) = pv;
      }
      {
        int n = tl * 16 + (cl & 15);
        const float* wp = &W[(size_t)k * D_H + n];
        uint4 qv;
        qv.x = (unsigned)f2bf(wp[0])   | ((unsigned)f2bf(wp[64])  << 16);
        qv.y = (unsigned)f2bf(wp[128]) | ((unsigned)f2bf(wp[192]) << 16);
        qv.z = (unsigned)f2bf(wp[256]) | ((unsigned)f2bf(wp[320]) << 16);
        qv.w = (unsigned)f2bf(wp[384]) | ((unsigned)f2bf(wp[448]) << 16);
        *reinterpret_cast<uint4*>(&b_sw[id * 8]) = qv;
      }
    }
    __syncthreads();
    #pragma unroll
    for (int s = 0; s < 4; s++){
      short8 a = *reinterpret_cast<const short8*>(&a_sw[((w * 4 + s) * 64 + l) * 8]);
      #pragma unroll
      for (int nt = 0; nt < 4; nt++){
        short8 b = *reinterpret_cast<const short8*>(&b_sw[((nt * 4 + s) * 64 + l) * 8]);
        acc[nt] = __builtin_amdgcn_mfma_f32_16x16x32_bf16(a, b, acc[nt], 0, 0, 0);
      }
    }
    __syncthreads();
  }
  const int qd = l >> 4;
  const int col0 = l & 15;
  #pragma unroll
  for (int r = 0; r < 4; r++){
    int node = node0 + w * 16 + qd * 4 + r;
    if (node < N){
      float scale = dis[node];
      #pragma unroll
      for (int nt = 0; nt < 4; nt++)
        hb[(size_t)node * D_H + nt * 16 + col0] = f2bf(acc[nt][r] * scale);
    }
  }
}

// ---- K6: aggregation: wave per node, lane = feature, contiguous csr gather ----
// messages pre-scaled by dis[src]; factor dis[dst] out; no atomics anywhere.
__global__ void k_agg(const unsigned short* __restrict__ hb,
                      const int* __restrict__ csr, const int* __restrict__ rowstart,
                      const float* __restrict__ dis, const float* __restrict__ bg,
                      float* __restrict__ hout, int N){
  int gid = blockIdx.x * blockDim.x + threadIdx.x;
  int i = gid >> 6;
  int f = gid & 63;
  if (i >= N) return;
  float acc = bf2f(hb[(size_t)i * D_H + f]);   // self-loop term h[i]*dis[i]
  int rs = rowstart[i];
  int re = rowstart[i + 1];
  int e = rs;
  for (; e + 4 <= re; e += 4){
    int s0 = csr[e], s1 = csr[e + 1], s2 = csr[e + 2], s3 = csr[e + 3];
    float v0 = bf2f(hb[(size_t)s0 * D_H + f]);
    float v1 = bf2f(hb[(size_t)s1 * D_H + f]);
    float v2 = bf2f(hb[(size_t)s2 * D_H + f]);
    float v3 = bf2f(hb[(size_t)s3 * D_H + f]);
    acc += (v0 + v1) + (v2 + v3);
  }
  for (; e < re; e++)
    acc += bf2f(hb[(size_t)csr[e] * D_H + f]);
  float v = acc * dis[i] + bg[f];
  hout[(size_t)i * D_H + f] = v > 0.f ? v : 0.f;
}

// ---- K7: pool (sorted batch -> binary search range) + classifier ----
__global__ void k_pool(const float* __restrict__ hout, const int* __restrict__ batch,
                       const float* __restrict__ wc, const float* __restrict__ bc,
                       float* __restrict__ out, int N, int G){
  int g = blockIdx.x;
  int t = threadIdx.x;
  int lo = 0, hi = N;
  while (lo < hi){ int m = (lo + hi) >> 1; if (batch[m] < g) lo = m + 1; else hi = m; }
  int start = lo;
  lo = start; hi = N;
  while (lo < hi){ int m = (lo + hi) >> 1; if (batch[m] < g + 1) lo = m + 1; else hi = m; }
  int end = lo;

  int f = t & 63;
  int r = t >> 6;
  float sum = 0.f;
  for (int i = start + r; i < end; i += 4) sum += hout[(size_t)i * D_H + f];
  __shared__ float red[256];
  red[t] = sum;
  __syncthreads();
  if (t < 64){
    float z = red[t] + red[t + 64] + red[t + 128] + red[t + 192];
    float p = z * wc[t];
    #pragma unroll
    for (int off = 32; off > 0; off >>= 1) p += __shfl_down(p, off);
    if (t == 0) out[g] = p + bc[0];
  }
}

extern "C" void kernel_launch(void* const* d_in, const int* in_sizes, int n_in,
                              void* d_out, int out_size, void* d_ws, size_t ws_size,
                              hipStream_t stream){
  const float* x     = (const float*)d_in[0];
  const int*   ei    = (const int*)d_in[1];    // [2,E] flat: [0..E)=src, [E..2E)=dst
  const int*   batch = (const int*)d_in[2];
  const float* Wg    = (const float*)d_in[3];
  const float* bg    = (const float*)d_in[4];
  const float* wc    = (const float*)d_in[5];
  const float* bc    = (const float*)d_in[6];
  float* out = (float*)d_out;

  const int N = in_sizes[2];
  const int E = in_sizes[1] / 2;
  const int G = out_size;
  const int NB = (N + BN - 1) / BN;   // 782 for N=100000 (<=1024 assumed)

  char* ws = (char*)d_ws;
  size_t off = 0;
  auto alloc = [&](size_t bytes) -> void* {
    void* p = ws + off;
    off += (bytes + 255) & ~(size_t)255;
    return p;
  };
  int*            bcnt     = (int*)           alloc((size_t)NB * PAD * 4);
  int*            bcur     = (int*)           alloc((size_t)NB * PAD * 4);
  int*            bstart   = (int*)           alloc((size_t)(NB + 1) * 4);
  unsigned*       bscat    = (unsigned*)      alloc((size_t)E * 4);
  int*            csr      = (int*)           alloc((size_t)E * 4);
  int*            rowstart = (int*)           alloc((size_t)(N + 1) * 4);
  float*          dis      = (float*)         alloc((size_t)N * 4);
  unsigned short* hb       = (unsigned short*)alloc((size_t)N * D_H * 2);
  float*          hout     = (float*)         alloc((size_t)N * D_H * 4);

  k_binit   <<<(NB * PAD + 255) / 256, 256, 0, stream>>>(bcnt, NB * PAD);
  k_bcount  <<<512, 256, 0, stream>>>(ei, bcnt, E, NB);
  k_bscan   <<<1, 1024, 0, stream>>>(bcnt, bstart, bcur, NB, E);
  k_bscatter<<<(E + 255) / 256, 256, 0, stream>>>(ei, bcur, bscat, E);
  k_nodecsr <<<NB, 256, 0, stream>>>(bscat, bstart, csr, rowstart, dis, N, NB, E);
  k_gemm    <<<(N + 63) / 64, 256, 0, stream>>>(x, Wg, dis, hb, N);
  k_agg     <<<(N + 3) / 4, 256, 0, stream>>>(hb, csr, rowstart, dis, bg, hout, N);
  k_pool    <<<G, 256, 0, stream>>>(hout, batch, wc, bc, out, N, G);
}

// Round 5
// 476.854 us; speedup vs baseline: 3.8820x; 1.2789x over previous
//
#include <hip/hip_runtime.h>
#include <hip/hip_bf16.h>

#define D_IN 384
#define D_H  64
#define BSH  7          // bucket shift: 128 nodes per bucket
#define BN   128        // nodes per bucket
#define NBLK 512        // chunks for the two-level counting sort
#define EBUF 4608       // staged edges per bucket (mean 4092, +8 sigma margin)

typedef __attribute__((ext_vector_type(8))) short short8;
typedef __attribute__((ext_vector_type(4))) float f32x4;

__device__ __forceinline__ unsigned short f2bf(float f){
  unsigned u = __float_as_uint(f);
  u += 0x7fffu + ((u >> 16) & 1u);   // round-to-nearest-even
  return (unsigned short)(u >> 16);
}
__device__ __forceinline__ float bf2f(unsigned short u){
  return __uint_as_float((unsigned)u << 16);
}

// ---- K1: per-chunk LDS histogram of dst buckets -> hists[blk][NB] ----
__global__ __launch_bounds__(256) void k_bcount2(const int* __restrict__ ei,
                                                 int* __restrict__ hists,
                                                 int E, int NB, int chunk){
  __shared__ int hist[1024];
  const int blk = blockIdx.x;
  const int t = threadIdx.x;
  for (int i = t; i < NB; i += 256) hist[i] = 0;
  __syncthreads();
  const int cs = blk * chunk;
  const int ce = min(E, cs + chunk);
  for (int e = cs + t; e < ce; e += 256)
    atomicAdd(&hist[ei[E + e] >> BSH], 1);
  __syncthreads();
  for (int i = t; i < NB; i += 256)
    hists[(size_t)blk * NB + i] = hist[i];
}

// ---- K2: per-bucket scan across blocks -> offs[b][blk] (exclusive), bsum[b] ----
__global__ __launch_bounds__(NBLK) void k_blkscan(const int* __restrict__ hists,
                                                  int* __restrict__ offs,
                                                  int* __restrict__ bsum, int NB){
  __shared__ int sd[NBLK];
  const int b = blockIdx.x;
  const int t = threadIdx.x;
  int c = hists[(size_t)t * NB + b];
  sd[t] = c;
  __syncthreads();
  for (int off = 1; off < NBLK; off <<= 1){
    int v = (t >= off) ? sd[t - off] : 0;
    __syncthreads();
    sd[t] += v;
    __syncthreads();
  }
  offs[(size_t)b * NBLK + t] = sd[t] - c;   // exclusive within bucket
  if (t == NBLK - 1) bsum[b] = sd[t];
}

// ---- K3: single-block scan over bucket totals -> bstart ----
__global__ __launch_bounds__(1024) void k_bscan(const int* __restrict__ bsum,
                                                int* bstart, int NB, int E){
  __shared__ int sd[1024];
  int t = threadIdx.x;
  int c = (t < NB) ? bsum[t] : 0;
  sd[t] = c;
  __syncthreads();
  for (int off = 1; off < 1024; off <<= 1){
    int v = (t >= off) ? sd[t - off] : 0;
    __syncthreads();
    sd[t] += v;
    __syncthreads();
  }
  if (t < NB) bstart[t] = sd[t] - c;
  if (t == 0) bstart[NB] = E;
}

// ---- K4: rank-and-scatter; each (block,bucket) segment is single-CU-owned ----
__global__ __launch_bounds__(256) void k_bscatter2(const int* __restrict__ ei,
                                                   const int* __restrict__ bstart,
                                                   const int* __restrict__ offs,
                                                   unsigned* __restrict__ bscat,
                                                   int E, int NB, int chunk){
  __shared__ int lcur[1024];
  const int blk = blockIdx.x;
  const int t = threadIdx.x;
  for (int i = t; i < NB; i += 256)
    lcur[i] = bstart[i] + offs[(size_t)i * NBLK + blk];
  __syncthreads();
  const int cs = blk * chunk;
  const int ce = min(E, cs + chunk);
  for (int e = cs + t; e < ce; e += 256){
    int s = ei[e];
    int d = ei[E + e];
    int b = d >> BSH;
    int pos = atomicAdd(&lcur[b], 1);
    bscat[pos] = ((unsigned)(d & (BN - 1)) << 17) | (unsigned)s;
  }
}

// ---- K5: per-bucket counting sort -> node-major csr, rowstart, dis ----
__global__ __launch_bounds__(256) void k_nodecsr(const unsigned* __restrict__ bscat,
                                                 const int* __restrict__ bstart,
                                                 int* __restrict__ csr,
                                                 int* __restrict__ rowstart,
                                                 float* __restrict__ dis,
                                                 int N, int NB, int E){
  __shared__ int lcnt[BN];
  __shared__ int sc[BN];
  __shared__ int lcur[BN];
  __shared__ unsigned ebuf[EBUF];
  const int b = blockIdx.x;
  const int t = threadIdx.x;
  const int es = bstart[b], ee = bstart[b + 1];
  const int cnt = ee - es;

  if (t < BN) lcnt[t] = 0;
  __syncthreads();
  for (int i = t; i < cnt; i += 256){
    unsigned p = bscat[es + i];
    if (i < EBUF) ebuf[i] = p;
    atomicAdd(&lcnt[p >> 17], 1);
  }
  __syncthreads();
  if (t < BN) sc[t] = lcnt[t];
  __syncthreads();
  for (int off = 1; off < BN; off <<= 1){
    int v = (t < BN && t >= off) ? sc[t - off] : 0;
    __syncthreads();
    if (t < BN) sc[t] += v;
    __syncthreads();
  }
  if (t < BN){
    int excl = sc[t] - lcnt[t];
    lcur[t] = excl;
    int node = b * BN + t;
    if (node < N){
      rowstart[node] = es + excl;
      dis[node] = rsqrtf((float)(lcnt[t] + 1));
    }
  }
  if (b == NB - 1 && t == 0) rowstart[N] = E;
  __syncthreads();
  for (int i = t; i < cnt; i += 256){
    unsigned p = (i < EBUF) ? ebuf[i] : bscat[es + i];
    int pos = atomicAdd(&lcur[p >> 17], 1);
    csr[es + pos] = (int)(p & 0x1FFFFu);
  }
}

// ---- K6: hb = bf16( (x @ W_gcn) * dis[row] )  -- pre-scaled by dis[src] ----
__global__ __launch_bounds__(256) void k_gemm(const float* __restrict__ x,
                                              const float* __restrict__ W,
                                              const float* __restrict__ dis,
                                              unsigned short* __restrict__ hb, int N){
  __shared__ __align__(16) short a_sw[4 * 4 * 64 * 8];  // 16 KiB
  __shared__ __align__(16) short b_sw[4 * 4 * 64 * 8];  // 16 KiB
  const int t = threadIdx.x;
  const int node0 = blockIdx.x * 64;
  const int w = t >> 6;
  const int l = t & 63;

  f32x4 acc[4];
  #pragma unroll
  for (int nt = 0; nt < 4; nt++) acc[nt] = (f32x4){0.f, 0.f, 0.f, 0.f};

  for (int c = 0; c < 3; c++){
    const int kbase = c * 128;
    #pragma unroll
    for (int r = 0; r < 4; r++){
      int id  = t + 256 * r;
      int cl  = id & 63;
      int s   = (id >> 6) & 3;
      int tl  = id >> 8;
      int k   = kbase + s * 32 + ((cl >> 4) << 3);
      {
        int node = node0 + tl * 16 + (cl & 15);
        uint4 pv;
        if (node < N){
          const float* xp = &x[(size_t)node * D_IN + k];
          float4 u0 = *(const float4*)xp;
          float4 u1 = *(const float4*)(xp + 4);
          pv.x = (unsigned)f2bf(u0.x) | ((unsigned)f2bf(u0.y) << 16);
          pv.y = (unsigned)f2bf(u0.z) | ((unsigned)f2bf(u0.w) << 16);
          pv.z = (unsigned)f2bf(u1.x) | ((unsigned)f2bf(u1.y) << 16);
          pv.w = (unsigned)f2bf(u1.z) | ((unsigned)f2bf(u1.w) << 16);
        } else {
          pv.x = pv.y = pv.z = pv.w = 0u;
        }
        *reinterpret_cast<uint4*>(&a_sw[id * 8]) = pv;
      }
      {
        int n = tl * 16 + (cl & 15);
        const float* wp = &W[(size_t)k * D_H + n];
        uint4 qv;
        qv.x = (unsigned)f2bf(wp[0])   | ((unsigned)f2bf(wp[64])  << 16);
        qv.y = (unsigned)f2bf(wp[128]) | ((unsigned)f2bf(wp[192]) << 16);
        qv.z = (unsigned)f2bf(wp[256]) | ((unsigned)f2bf(wp[320]) << 16);
        qv.w = (unsigned)f2bf(wp[384]) | ((unsigned)f2bf(wp[448]) << 16);
        *reinterpret_cast<uint4*>(&b_sw[id * 8]) = qv;
      }
    }
    __syncthreads();
    #pragma unroll
    for (int s = 0; s < 4; s++){
      short8 a = *reinterpret_cast<const short8*>(&a_sw[((w * 4 + s) * 64 + l) * 8]);
      #pragma unroll
      for (int nt = 0; nt < 4; nt++){
        short8 b = *reinterpret_cast<const short8*>(&b_sw[((nt * 4 + s) * 64 + l) * 8]);
        acc[nt] = __builtin_amdgcn_mfma_f32_16x16x32_bf16(a, b, acc[nt], 0, 0, 0);
      }
    }
    __syncthreads();
  }
  const int qd = l >> 4;
  const int col0 = l & 15;
  #pragma unroll
  for (int r = 0; r < 4; r++){
    int node = node0 + w * 16 + qd * 4 + r;
    if (node < N){
      float scale = dis[node];
      #pragma unroll
      for (int nt = 0; nt < 4; nt++)
        hb[(size_t)node * D_H + nt * 16 + col0] = f2bf(acc[nt][r] * scale);
    }
  }
}

// ---- K7: aggregation: wave per node, lane = feature, contiguous csr gather ----
__global__ void k_agg(const unsigned short* __restrict__ hb,
                      const int* __restrict__ csr, const int* __restrict__ rowstart,
                      const float* __restrict__ dis, const float* __restrict__ bg,
                      float* __restrict__ hout, int N){
  int gid = blockIdx.x * blockDim.x + threadIdx.x;
  int i = gid >> 6;
  int f = gid & 63;
  if (i >= N) return;
  float acc = bf2f(hb[(size_t)i * D_H + f]);   // self-loop term h[i]*dis[i]
  int rs = rowstart[i];
  int re = rowstart[i + 1];
  int e = rs;
  for (; e + 4 <= re; e += 4){
    int s0 = csr[e], s1 = csr[e + 1], s2 = csr[e + 2], s3 = csr[e + 3];
    float v0 = bf2f(hb[(size_t)s0 * D_H + f]);
    float v1 = bf2f(hb[(size_t)s1 * D_H + f]);
    float v2 = bf2f(hb[(size_t)s2 * D_H + f]);
    float v3 = bf2f(hb[(size_t)s3 * D_H + f]);
    acc += (v0 + v1) + (v2 + v3);
  }
  for (; e < re; e++)
    acc += bf2f(hb[(size_t)csr[e] * D_H + f]);
  float v = acc * dis[i] + bg[f];
  hout[(size_t)i * D_H + f] = v > 0.f ? v : 0.f;
}

// ---- K8: pool (sorted batch -> binary search range) + classifier ----
__global__ void k_pool(const float* __restrict__ hout, const int* __restrict__ batch,
                       const float* __restrict__ wc, const float* __restrict__ bc,
                       float* __restrict__ out, int N, int G){
  int g = blockIdx.x;
  int t = threadIdx.x;
  int lo = 0, hi = N;
  while (lo < hi){ int m = (lo + hi) >> 1; if (batch[m] < g) lo = m + 1; else hi = m; }
  int start = lo;
  lo = start; hi = N;
  while (lo < hi){ int m = (lo + hi) >> 1; if (batch[m] < g + 1) lo = m + 1; else hi = m; }
  int end = lo;

  int f = t & 63;
  int r = t >> 6;
  float sum = 0.f;
  for (int i = start + r; i < end; i += 4) sum += hout[(size_t)i * D_H + f];
  __shared__ float red[256];
  red[t] = sum;
  __syncthreads();
  if (t < 64){
    float z = red[t] + red[t + 64] + red[t + 128] + red[t + 192];
    float p = z * wc[t];
    #pragma unroll
    for (int off = 32; off > 0; off >>= 1) p += __shfl_down(p, off);
    if (t == 0) out[g] = p + bc[0];
  }
}

extern "C" void kernel_launch(void* const* d_in, const int* in_sizes, int n_in,
                              void* d_out, int out_size, void* d_ws, size_t ws_size,
                              hipStream_t stream){
  const float* x     = (const float*)d_in[0];
  const int*   ei    = (const int*)d_in[1];    // [2,E] flat: [0..E)=src, [E..2E)=dst
  const int*   batch = (const int*)d_in[2];
  const float* Wg    = (const float*)d_in[3];
  const float* bg    = (const float*)d_in[4];
  const float* wc    = (const float*)d_in[5];
  const float* bc    = (const float*)d_in[6];
  float* out = (float*)d_out;

  const int N = in_sizes[2];
  const int E = in_sizes[1] / 2;
  const int G = out_size;
  const int NB = (N + BN - 1) / BN;          // 782 for N=100000 (<=1024 assumed)
  const int chunk = (E + NBLK - 1) / NBLK;   // edges per sort chunk

  char* ws = (char*)d_ws;
  size_t off = 0;
  auto alloc = [&](size_t bytes) -> void* {
    void* p = ws + off;
    off += (bytes + 255) & ~(size_t)255;
    return p;
  };
  int*            hists    = (int*)           alloc((size_t)NBLK * NB * 4);
  int*            offs     = (int*)           alloc((size_t)NB * NBLK * 4);
  int*            bsum     = (int*)           alloc((size_t)NB * 4);
  int*            bstart   = (int*)           alloc((size_t)(NB + 1) * 4);
  unsigned*       bscat    = (unsigned*)      alloc((size_t)E * 4);
  int*            csr      = (int*)           alloc((size_t)E * 4);
  int*            rowstart = (int*)           alloc((size_t)(N + 1) * 4);
  float*          dis      = (float*)         alloc((size_t)N * 4);
  unsigned short* hb       = (unsigned short*)alloc((size_t)N * D_H * 2);
  float*          hout     = (float*)         alloc((size_t)N * D_H * 4);

  k_bcount2  <<<NBLK, 256, 0, stream>>>(ei, hists, E, NB, chunk);
  k_blkscan  <<<NB, NBLK, 0, stream>>>(hists, offs, bsum, NB);
  k_bscan    <<<1, 1024, 0, stream>>>(bsum, bstart, NB, E);
  k_bscatter2<<<NBLK, 256, 0, stream>>>(ei, bstart, offs, bscat, E, NB, chunk);
  k_nodecsr  <<<NB, 256, 0, stream>>>(bscat, bstart, csr, rowstart, dis, N, NB, E);
  k_gemm     <<<(N + 63) / 64, 256, 0, stream>>>(x, Wg, dis, hb, N);
  k_agg      <<<(N + 3) / 4, 256, 0, stream>>>(hb, csr, rowstart, dis, bg, hout, N);
  k_pool     <<<G, 256, 0, stream>>>(hout, batch, wc, bc, out, N, G);
}

// Round 6
// 439.860 us; speedup vs baseline: 4.2085x; 1.0841x over previous
//
#include <hip/hip_runtime.h>
#include <hip/hip_bf16.h>

#define D_IN 384
#define D_H  64
#define BSH  7          // bucket shift: 128 nodes per bucket
#define BN   128        // nodes per bucket
#define NBLK 512        // chunks for the two-level counting sort
#define EBUF 4608       // staged edges per bucket (mean 4096, +8 sigma margin)

typedef __attribute__((ext_vector_type(8))) short short8;
typedef __attribute__((ext_vector_type(4))) float f32x4;

__device__ __forceinline__ unsigned f2bf(float f){
  unsigned u = __float_as_uint(f);
  u += 0x7fffu + ((u >> 16) & 1u);   // round-to-nearest-even
  return u >> 16;
}
__device__ __forceinline__ float bf2f(unsigned short u){
  return __uint_as_float((unsigned)u << 16);
}

// ---- K1: per-chunk LDS histogram of dst buckets -> hists[blk][NB] ----
__global__ __launch_bounds__(256) void k_bcount2(const int* __restrict__ ei,
                                                 int* __restrict__ hists,
                                                 int E, int NB, int chunk){
  __shared__ int hist[1024];
  const int blk = blockIdx.x;
  const int t = threadIdx.x;
  for (int i = t; i < NB; i += 256) hist[i] = 0;
  __syncthreads();
  const int cs = blk * chunk;
  const int ce = min(E, cs + chunk);
  for (int e = cs + t; e < ce; e += 256)
    atomicAdd(&hist[ei[E + e] >> BSH], 1);
  __syncthreads();
  for (int i = t; i < NB; i += 256)
    hists[(size_t)blk * NB + i] = hist[i];
}

// ---- K2: per-bucket scan across blocks -> offs[b][blk] (exclusive), bsum[b] ----
__global__ __launch_bounds__(NBLK) void k_blkscan(const int* __restrict__ hists,
                                                  int* __restrict__ offs,
                                                  int* __restrict__ bsum, int NB){
  __shared__ int sd[NBLK];
  const int b = blockIdx.x;
  const int t = threadIdx.x;
  int c = hists[(size_t)t * NB + b];
  sd[t] = c;
  __syncthreads();
  for (int off = 1; off < NBLK; off <<= 1){
    int v = (t >= off) ? sd[t - off] : 0;
    __syncthreads();
    sd[t] += v;
    __syncthreads();
  }
  offs[(size_t)b * NBLK + t] = sd[t] - c;   // exclusive within bucket
  if (t == NBLK - 1) bsum[b] = sd[t];
}

// ---- K3: single-block scan over bucket totals -> bstart ----
__global__ __launch_bounds__(1024) void k_bscan(const int* __restrict__ bsum,
                                                int* bstart, int NB, int E){
  __shared__ int sd[1024];
  int t = threadIdx.x;
  int c = (t < NB) ? bsum[t] : 0;
  sd[t] = c;
  __syncthreads();
  for (int off = 1; off < 1024; off <<= 1){
    int v = (t >= off) ? sd[t - off] : 0;
    __syncthreads();
    sd[t] += v;
    __syncthreads();
  }
  if (t < NB) bstart[t] = sd[t] - c;
  if (t == 0) bstart[NB] = E;
}

// ---- K4: rank-and-scatter; each (block,bucket) segment is single-CU-owned ----
__global__ __launch_bounds__(256) void k_bscatter2(const int* __restrict__ ei,
                                                   const int* __restrict__ bstart,
                                                   const int* __restrict__ offs,
                                                   unsigned* __restrict__ bscat,
                                                   int E, int NB, int chunk){
  __shared__ int lcur[1024];
  const int blk = blockIdx.x;
  const int t = threadIdx.x;
  for (int i = t; i < NB; i += 256)
    lcur[i] = bstart[i] + offs[(size_t)i * NBLK + blk];
  __syncthreads();
  const int cs = blk * chunk;
  const int ce = min(E, cs + chunk);
  for (int e = cs + t; e < ce; e += 256){
    int s = ei[e];
    int d = ei[E + e];
    int b = d >> BSH;
    int pos = atomicAdd(&lcur[b], 1);
    bscat[pos] = ((unsigned)(d & (BN - 1)) << 17) | (unsigned)s;
  }
}

// ---- K5: per-bucket counting sort -> node-major csr (BYTE offsets src<<7),
//          rowstart, dis ----
__global__ __launch_bounds__(256) void k_nodecsr(const unsigned* __restrict__ bscat,
                                                 const int* __restrict__ bstart,
                                                 int* __restrict__ csr,
                                                 int* __restrict__ rowstart,
                                                 float* __restrict__ dis,
                                                 int N, int NB, int E){
  __shared__ int lcnt[BN];
  __shared__ int sc[BN];
  __shared__ int lcur[BN];
  __shared__ unsigned ebuf[EBUF];
  const int b = blockIdx.x;
  const int t = threadIdx.x;
  const int es = bstart[b], ee = bstart[b + 1];
  const int cnt = ee - es;

  if (t < BN) lcnt[t] = 0;
  __syncthreads();
  for (int i = t; i < cnt; i += 256){
    unsigned p = bscat[es + i];
    if (i < EBUF) ebuf[i] = p;
    atomicAdd(&lcnt[p >> 17], 1);
  }
  __syncthreads();
  if (t < BN) sc[t] = lcnt[t];
  __syncthreads();
  for (int off = 1; off < BN; off <<= 1){
    int v = (t < BN && t >= off) ? sc[t - off] : 0;
    __syncthreads();
    if (t < BN) sc[t] += v;
    __syncthreads();
  }
  if (t < BN){
    int excl = sc[t] - lcnt[t];
    lcur[t] = excl;
    int node = b * BN + t;
    if (node < N){
      rowstart[node] = es + excl;
      dis[node] = rsqrtf((float)(lcnt[t] + 1));
    }
  }
  if (b == NB - 1 && t == 0) rowstart[N] = E;
  __syncthreads();
  for (int i = t; i < cnt; i += 256){
    unsigned p = (i < EBUF) ? ebuf[i] : bscat[es + i];
    int pos = atomicAdd(&lcur[p >> 17], 1);
    csr[es + pos] = (int)((p & 0x1FFFFu) << 7);   // byte offset of hb row
  }
}

// ---- K6a: pre-swizzle W into B-fragment order, bf16 (once, 48 KB) ----
// b_pre[c*1024 + (nt*4+s)*64 + l] = W[k..k+8 (stride 64)][nt*16 + (l&15)],
// k = c*128 + s*32 + ((l>>4)<<3)
__global__ void k_wconv(const float* __restrict__ W, uint4* __restrict__ bpre){
  int j = blockIdx.x * blockDim.x + threadIdx.x;
  if (j >= 3072) return;
  int id = j & 1023, c = j >> 10;
  int cl = id & 63, s = (id >> 6) & 3, tl = id >> 8;
  int k = c * 128 + s * 32 + ((cl >> 4) << 3);
  int n = tl * 16 + (cl & 15);
  const float* wp = &W[(size_t)k * D_H + n];
  uint4 qv;
  qv.x = f2bf(wp[0])   | (f2bf(wp[64])  << 16);
  qv.y = f2bf(wp[128]) | (f2bf(wp[192]) << 16);
  qv.z = f2bf(wp[256]) | (f2bf(wp[320]) << 16);
  qv.w = f2bf(wp[384]) | (f2bf(wp[448]) << 16);
  bpre[j] = qv;
}

// ---- K6: LDS-free GEMM: hb = bf16( (x @ W_gcn) * dis[row] ) ----
// A-fragments built in-register from x (per-wave-private anyway);
// B-fragments read pre-swizzled from L2-resident bpre. No LDS, no barriers.
__global__ __launch_bounds__(256) void k_gemm(const float* __restrict__ x,
                                              const uint4* __restrict__ bpre,
                                              const float* __restrict__ dis,
                                              unsigned short* __restrict__ hb, int N){
  const int t = threadIdx.x;
  const int w = t >> 6;
  const int l = t & 63;
  const int node0 = blockIdx.x * 64;
  const int row = node0 + w * 16 + (l & 15);
  const int rowc = row < N ? row : N - 1;
  const float* xr = x + (size_t)rowc * D_IN + ((l >> 4) << 3);

  f32x4 acc[4];
  #pragma unroll
  for (int nt = 0; nt < 4; nt++) acc[nt] = (f32x4){0.f, 0.f, 0.f, 0.f};

  #pragma unroll
  for (int c = 0; c < 3; c++){
    #pragma unroll
    for (int s = 0; s < 4; s++){
      const float* xp = xr + c * 128 + s * 32;
      float4 u0 = *(const float4*)xp;
      float4 u1 = *(const float4*)(xp + 4);
      uint4 pv;
      pv.x = f2bf(u0.x) | (f2bf(u0.y) << 16);
      pv.y = f2bf(u0.z) | (f2bf(u0.w) << 16);
      pv.z = f2bf(u1.x) | (f2bf(u1.y) << 16);
      pv.w = f2bf(u1.z) | (f2bf(u1.w) << 16);
      short8 a = *reinterpret_cast<short8*>(&pv);
      #pragma unroll
      for (int nt = 0; nt < 4; nt++){
        short8 b = *reinterpret_cast<const short8*>(&bpre[c * 1024 + (nt * 4 + s) * 64 + l]);
        acc[nt] = __builtin_amdgcn_mfma_f32_16x16x32_bf16(a, b, acc[nt], 0, 0, 0);
      }
    }
  }
  // epilogue: C/D layout col = lane&15, row = (lane>>4)*4 + reg; scale by dis
  const int qd = l >> 4;
  const int col0 = l & 15;
  #pragma unroll
  for (int r = 0; r < 4; r++){
    int node = node0 + w * 16 + qd * 4 + r;
    if (node < N){
      float scale = dis[node];
      #pragma unroll
      for (int nt = 0; nt < 4; nt++)
        hb[(size_t)node * D_H + nt * 16 + col0] = (unsigned short)f2bf(acc[nt][r] * scale);
    }
  }
}

// ---- K7: pair-gather aggregation ----
// wave per node; lane covers a feature PAIR (uint = 2 bf16); lanes 0-31 gather
// edge e's row, lanes 32-63 edge e+1's -> one load instr covers 2 edges.
// csr holds byte offsets (src<<7). Final shfl_xor(32) merges the halves.
__global__ __launch_bounds__(256) void k_agg(const unsigned short* __restrict__ hb,
                                             const int* __restrict__ csr,
                                             const int* __restrict__ rowstart,
                                             const float* __restrict__ dis,
                                             const float* __restrict__ bg,
                                             float* __restrict__ hout, int N){
  int gid = blockIdx.x * 256 + (int)threadIdx.x;
  int i = __builtin_amdgcn_readfirstlane(gid >> 6);
  if (i >= N) return;
  const int l = threadIdx.x & 63;
  const int c4 = (l & 31) << 2;      // byte offset of this lane's uint in a row
  const int hsel = l >> 5;           // 0 = low half (edge e), 1 = high (edge e+1)
  const char* hbb = (const char*)hb;
  float ax = 0.f, ay = 0.f;

  // self-loop term hb[i] (= h[i]*dis[i]) — count once (low half only)
  {
    unsigned u = *(const unsigned*)(hbb + ((size_t)(unsigned)i << 7) + c4);
    if (!hsel){
      ax += __uint_as_float(u << 16);
      ay += __uint_as_float(u & 0xffff0000u);
    }
  }
  int e = rowstart[i];
  const int re = rowstart[i + 1];
  for (; e + 8 <= re; e += 8){
    int b0 = csr[e + 0], b1 = csr[e + 1];
    int b2 = csr[e + 2], b3 = csr[e + 3];
    int b4 = csr[e + 4], b5 = csr[e + 5];
    int b6 = csr[e + 6], b7 = csr[e + 7];
    unsigned u0 = *(const unsigned*)(hbb + (size_t)(unsigned)(hsel ? b1 : b0) + c4);
    unsigned u1 = *(const unsigned*)(hbb + (size_t)(unsigned)(hsel ? b3 : b2) + c4);
    unsigned u2 = *(const unsigned*)(hbb + (size_t)(unsigned)(hsel ? b5 : b4) + c4);
    unsigned u3 = *(const unsigned*)(hbb + (size_t)(unsigned)(hsel ? b7 : b6) + c4);
    ax += __uint_as_float(u0 << 16);          ay += __uint_as_float(u0 & 0xffff0000u);
    ax += __uint_as_float(u1 << 16);          ay += __uint_as_float(u1 & 0xffff0000u);
    ax += __uint_as_float(u2 << 16);          ay += __uint_as_float(u2 & 0xffff0000u);
    ax += __uint_as_float(u3 << 16);          ay += __uint_as_float(u3 & 0xffff0000u);
  }
  for (; e + 2 <= re; e += 2){
    int b0 = csr[e], b1 = csr[e + 1];
    unsigned u = *(const unsigned*)(hbb + (size_t)(unsigned)(hsel ? b1 : b0) + c4);
    ax += __uint_as_float(u << 16);
    ay += __uint_as_float(u & 0xffff0000u);
  }
  if (e < re){
    int b0 = csr[e];
    unsigned u = *(const unsigned*)(hbb + (size_t)(unsigned)b0 + c4);
    if (!hsel){
      ax += __uint_as_float(u << 16);
      ay += __uint_as_float(u & 0xffff0000u);
    }
  }
  ax += __shfl_xor(ax, 32);
  ay += __shfl_xor(ay, 32);
  if (!hsel){
    float di = dis[i];
    float2 bb = *(const float2*)(bg + (c4 >> 1));
    float vx = ax * di + bb.x; vx = vx > 0.f ? vx : 0.f;
    float vy = ay * di + bb.y; vy = vy > 0.f ? vy : 0.f;
    float2 o = make_float2(vx, vy);
    *(float2*)((char*)hout + (((size_t)(unsigned)i) << 8) + (c4 << 1)) = o;
  }
}

// ---- K8: pool (sorted batch -> binary search range) + classifier ----
__global__ void k_pool(const float* __restrict__ hout, const int* __restrict__ batch,
                       const float* __restrict__ wc, const float* __restrict__ bc,
                       float* __restrict__ out, int N, int G){
  int g = blockIdx.x;
  int t = threadIdx.x;
  int lo = 0, hi = N;
  while (lo < hi){ int m = (lo + hi) >> 1; if (batch[m] < g) lo = m + 1; else hi = m; }
  int start = lo;
  lo = start; hi = N;
  while (lo < hi){ int m = (lo + hi) >> 1; if (batch[m] < g + 1) lo = m + 1; else hi = m; }
  int end = lo;

  int f = t & 63;
  int r = t >> 6;
  float sum = 0.f;
  for (int i = start + r; i < end; i += 4) sum += hout[(size_t)i * D_H + f];
  __shared__ float red[256];
  red[t] = sum;
  __syncthreads();
  if (t < 64){
    float z = red[t] + red[t + 64] + red[t + 128] + red[t + 192];
    float p = z * wc[t];
    #pragma unroll
    for (int off = 32; off > 0; off >>= 1) p += __shfl_down(p, off);
    if (t == 0) out[g] = p + bc[0];
  }
}

extern "C" void kernel_launch(void* const* d_in, const int* in_sizes, int n_in,
                              void* d_out, int out_size, void* d_ws, size_t ws_size,
                              hipStream_t stream){
  const float* x     = (const float*)d_in[0];
  const int*   ei    = (const int*)d_in[1];    // [2,E] flat: [0..E)=src, [E..2E)=dst
  const int*   batch = (const int*)d_in[2];
  const float* Wg    = (const float*)d_in[3];
  const float* bg    = (const float*)d_in[4];
  const float* wc    = (const float*)d_in[5];
  const float* bc    = (const float*)d_in[6];
  float* out = (float*)d_out;

  const int N = in_sizes[2];
  const int E = in_sizes[1] / 2;
  const int G = out_size;
  const int NB = (N + BN - 1) / BN;          // 782 for N=100000 (<=1024 assumed)
  const int chunk = (E + NBLK - 1) / NBLK;   // edges per sort chunk

  char* ws = (char*)d_ws;
  size_t off = 0;
  auto alloc = [&](size_t bytes) -> void* {
    void* p = ws + off;
    off += (bytes + 255) & ~(size_t)255;
    return p;
  };
  int*            hists    = (int*)           alloc((size_t)NBLK * NB * 4);
  int*            offs     = (int*)           alloc((size_t)NB * NBLK * 4);
  int*            bsum     = (int*)           alloc((size_t)NB * 4);
  int*            bstart   = (int*)           alloc((size_t)(NB + 1) * 4);
  unsigned*       bscat    = (unsigned*)      alloc((size_t)E * 4);
  int*            csr      = (int*)           alloc((size_t)E * 4);
  int*            rowstart = (int*)           alloc((size_t)(N + 1) * 4);
  float*          dis      = (float*)         alloc((size_t)N * 4);
  uint4*          bpre     = (uint4*)         alloc((size_t)3072 * 16);
  unsigned short* hb       = (unsigned short*)alloc((size_t)N * D_H * 2);
  float*          hout     = (float*)         alloc((size_t)N * D_H * 4);

  k_wconv    <<<12, 256, 0, stream>>>(Wg, bpre);
  k_bcount2  <<<NBLK, 256, 0, stream>>>(ei, hists, E, NB, chunk);
  k_blkscan  <<<NB, NBLK, 0, stream>>>(hists, offs, bsum, NB);
  k_bscan    <<<1, 1024, 0, stream>>>(bsum, bstart, NB, E);
  k_bscatter2<<<NBLK, 256, 0, stream>>>(ei, bstart, offs, bscat, E, NB, chunk);
  k_nodecsr  <<<NB, 256, 0, stream>>>(bscat, bstart, csr, rowstart, dis, N, NB, E);
  k_gemm     <<<(N + 63) / 64, 256, 0, stream>>>(x, bpre, dis, hb, N);
  k_agg      <<<(N + 3) / 4, 256, 0, stream>>>(hb, csr, rowstart, dis, bg, hout, N);
  k_pool     <<<G, 256, 0, stream>>>(hout, batch, wc, bc, out, N, G);
}